// Round 4
// baseline (2712.486 us; speedup 1.0000x reference)
//
#include <hip/hip_runtime.h>
#include <stdint.h>

#define DI __device__ __forceinline__

typedef __bf16 bf16;
typedef __bf16 bf16x8 __attribute__((ext_vector_type(8)));
typedef float  f32x4  __attribute__((ext_vector_type(4)));

// ---------------- problem constants ----------------
constexpr int Q = 256;
constexpr int BATCH = 65536;
constexpr int TM = 32;              // rows per block
constexpr int THREADS = 256;        // 4 waves
constexpr int NW = 4;
constexpr int NBLK = BATCH / TM;    // 2048
constexpr int SC = Q + 8;           // LDS row stride

// ---------------- workspace layout (packed bf16 weights, Wt[N][K] row-major) ----------------
constexpr int W0A_OFF = 0;                         // 3 x (768x256)
constexpr int W0B_OFF = W0A_OFF + 3*768*256;       // 3 x (256x768)
constexpr int W1A_OFF = W0B_OFF + 3*256*768;       // 3 x (512x256)
constexpr int W1B_OFF = W1A_OFF + 3*512*256;       // 3 x (256x512)
constexpr int WV_OFF  = W1B_OFF + 3*256*512;       // 2 x (256x256)  wqkv V-slice
constexpr int WO_OFF  = WV_OFF  + 2*256*256;       // 2 x (256x256)
constexpr int ENT_OFF = WO_OFF  + 2*256*256;       // 8 x (256x256)  tanh pre-applied
constexpr int NL1_OFF = ENT_OFF + 8*256*256;       // 4 x (256x256)
constexpr int NL2_OFF = NL1_OFF + 4*256*256;       // 4 x (256x256)
constexpr int WEND    = NL2_OFF + 4*256*256;
constexpr size_t F32_BYTE_OFF = (((size_t)WEND*2) + 255) & ~(size_t)255;

// f32 param region (element offsets)
constexpr int P_D0B1 = 0;                  // 3*768
constexpr int P_LNW  = P_D0B1 + 3*768;
constexpr int P_LNB  = P_LNW  + 3*768;
constexpr int P_D0B2 = P_LNB  + 3*768;     // 3*256
constexpr int P_D1B1 = P_D0B2 + 3*256;     // 3*512
constexpr int P_D1B2 = P_D1B1 + 3*512;     // 3*256
constexpr int P_BQV  = P_D1B2 + 3*256;     // 2*256
constexpr int P_BO   = P_BQV  + 2*256;     // 2*256
constexpr int P_NB1  = P_BO   + 2*256;     // 4*256
constexpr int P_NB2  = P_NB1  + 4*256;     // 4*256
constexpr int P_GLIN = P_NB2  + 4*256;     // 8*256
constexpr int P_GP3  = P_GLIN + 8*256;
constexpr int P_GP4  = P_GP3  + 8*256;
constexpr int P_GP5  = P_GP4  + 8*256;
constexpr int P_END  = P_GP5  + 8*256;     // 21,248 floats
constexpr size_t FLAG_OFF = F32_BYTE_OFF + (size_t)P_END*4;   // one int

// ---------------- dual-dtype load helper ----------------
DI float ldf(const void* p, size_t idx, int f32) {
  return f32 ? ((const float*)p)[idx] : (float)((const bf16*)p)[idx];
}

// ---------------- device math helpers ----------------
DI float tanh_fast(float x) {
  float ax = fabsf(x);
  float e  = __expf(-2.0f * ax);
  float r  = (1.0f - e) / (1.0f + e);
  return copysignf(r, x);
}

DI float gelu_f(float x) {   // exact-gelu via A&S 7.1.26 erf
  float ax = fabsf(x) * 0.70710678118654752f;
  float t  = 1.0f / (1.0f + 0.3275911f * ax);
  float y  = t*(0.254829592f + t*(-0.284496736f + t*(1.421413741f +
             t*(-1.453152027f + t*1.061405429f))));
  float er = copysignf(1.0f - y * __expf(-ax*ax), x);
  return 0.5f * x * (1.0f + er);
}

DI f32x4 mfma_bf16(uint4 a, uint4 b, f32x4 c) {
  return __builtin_amdgcn_mfma_f32_16x16x32_bf16(
      __builtin_bit_cast(bf16x8, a), __builtin_bit_cast(bf16x8, b), c, 0, 0, 0);
}

template<int NJ>
DI void zero_acc(f32x4 (&a)[2][NJ]) {
#pragma unroll
  for (int i = 0; i < 2; ++i)
#pragma unroll
    for (int j = 0; j < NJ; ++j) a[i][j] = f32x4{0.f, 0.f, 0.f, 0.f};
}

// D(32 x 16*4*NJ) += A(32x256 LDS, stride SC) * B-chunk from packed Bt[N][kdb],
// k in [koff, koff+256). n-tile index = nj*4 + wave.
template<int NJ>
DI void gemm_k256(const bf16* A, const bf16* __restrict__ Bt, int kdb, int koff,
                  f32x4 (&acc)[2][NJ], int wave, int quad, int l16) {
  const bf16* a0 = A + l16*SC + quad*8;
  const bf16* a1 = A + (16 + l16)*SC + quad*8;
  const bf16* br[NJ];
#pragma unroll
  for (int nj = 0; nj < NJ; ++nj)
    br[nj] = Bt + (size_t)((nj*4 + wave)*16 + l16)*kdb + koff + quad*8;
#pragma unroll
  for (int ks = 0; ks < 8; ++ks) {
    uint4 av0 = *(const uint4*)(a0 + ks*32);
    uint4 av1 = *(const uint4*)(a1 + ks*32);
#pragma unroll
    for (int nj = 0; nj < NJ; ++nj) {
      uint4 bv = *(const uint4*)(br[nj] + ks*32);
      acc[0][nj] = mfma_bf16(av0, bv, acc[0][nj]);
      acc[1][nj] = mfma_bf16(av1, bv, acc[1][nj]);
    }
  }
}

DI void addbias4(f32x4 (&a)[2][4], const float* __restrict__ b, int wave, int l16) {
#pragma unroll
  for (int nj = 0; nj < 4; ++nj) {
    float bb = b[(nj*4 + wave)*16 + l16];
#pragma unroll
    for (int mt = 0; mt < 2; ++mt)
#pragma unroll
      for (int reg = 0; reg < 4; ++reg) a[mt][nj][reg] += bb;
  }
}

DI void store4(bf16* dst, const f32x4 (&a)[2][4], int wave, int quad, int l16) {
#pragma unroll
  for (int nj = 0; nj < 4; ++nj) {
    int col = (nj*4 + wave)*16 + l16;
#pragma unroll
    for (int mt = 0; mt < 2; ++mt)
#pragma unroll
      for (int reg = 0; reg < 4; ++reg)
        dst[(mt*16 + quad*4 + reg)*SC + col] = (bf16)a[mt][nj][reg];
  }
}

// ---------------- dtype detector ----------------
// If x is f32, uint16 at EVEN index = low half of a float (mantissa bits) ->
// exponent-field uniform in 0..255. If x is bf16 (N(0,1) data), exponents <= ~130.
__global__ void detect_dtype(const uint16_t* __restrict__ xr, int* __restrict__ flag) {
  __shared__ int s_max;
  if (threadIdx.x == 0) s_max = 0;
  __syncthreads();
  int e = 0;
  for (int i = threadIdx.x; i < 4096; i += 256) {
    int ex = (xr[2*i] >> 7) & 0xFF;
    e = e > ex ? e : ex;
  }
  atomicMax(&s_max, e);
  __syncthreads();
  if (threadIdx.x == 0) *flag = (s_max >= 140) ? 1 : 0;
}

// ---------------- weight repack: W(KxN) -> Wt(NxK) bf16, optional tanh ----------------
__global__ void pack_weights(const void* __restrict__ d0w1, const void* __restrict__ d0w2,
                             const void* __restrict__ d1w1, const void* __restrict__ d1w2,
                             const void* __restrict__ wqkv, const void* __restrict__ wo,
                             const void* __restrict__ ent,  const void* __restrict__ nl1,
                             const void* __restrict__ nl2,  bf16* __restrict__ wsb,
                             const int* __restrict__ flag) {
  const int f32 = *flag;
  int job = blockIdx.y;
  const void* src; int mi, K, N, srcN, col0 = 0, dtanh = 0; long dst;
  if      (job < 3)  { src=d0w1; mi=job;    K=256; N=768; srcN=768; dst=W0A_OFF + (long)mi*768*256; }
  else if (job < 6)  { src=d0w2; mi=job-3;  K=768; N=256; srcN=256; dst=W0B_OFF + (long)mi*256*768; }
  else if (job < 9)  { src=d1w1; mi=job-6;  K=256; N=512; srcN=512; dst=W1A_OFF + (long)mi*512*256; }
  else if (job < 12) { src=d1w2; mi=job-9;  K=512; N=256; srcN=256; dst=W1B_OFF + (long)mi*256*512; }
  else if (job < 14) { src=wqkv; mi=job-12; K=256; N=256; srcN=768; col0=512; dst=WV_OFF + (long)mi*65536; }
  else if (job < 16) { src=wo;   mi=job-14; K=256; N=256; srcN=256; dst=WO_OFF + (long)mi*65536; }
  else if (job < 24) { src=ent;  mi=job-16; K=256; N=256; srcN=256; dst=ENT_OFF + (long)mi*65536; dtanh=1; }
  else if (job < 28) { src=nl1;  mi=job-24; K=256; N=256; srcN=256; dst=NL1_OFF + (long)mi*65536; }
  else               { src=nl2;  mi=job-28; K=256; N=256; srcN=256; dst=NL2_OFF + (long)mi*65536; }
  const size_t base = (size_t)mi * K * srcN;

  int tk = K/64, tn = N/64;
  int tile = blockIdx.x;
  if (tile >= tk*tn) return;
  int ik = tile % tk, in_ = tile / tk;

  __shared__ float t[64][65];
  int tid = threadIdx.x;
  for (int e = tid; e < 4096; e += 256) {
    int r = e >> 6, c = e & 63;
    t[r][c] = ldf(src, base + (size_t)(ik*64 + r)*srcN + col0 + in_*64 + c, f32);
  }
  __syncthreads();
  for (int e = tid; e < 4096; e += 256) {
    int nr = e >> 6, kc = e & 63;
    float v = t[kc][nr];
    if (dtanh) v = tanhf(v);
    wsb[dst + (size_t)(in_*64 + nr)*K + ik*64 + kc] = (bf16)v;
  }
}

// ---------------- param repack ----------------
__global__ void pack_params(const void* __restrict__ d0b1, const void* __restrict__ lnw,
                            const void* __restrict__ lnb,  const void* __restrict__ d0b2,
                            const void* __restrict__ d1b1, const void* __restrict__ d1b2,
                            const void* __restrict__ bqkv, const void* __restrict__ bo,
                            const void* __restrict__ gp,   const void* __restrict__ nb1,
                            const void* __restrict__ nb2,  float* __restrict__ wsf,
                            const int* __restrict__ flag) {
  const int f32 = *flag;
  int i = blockIdx.x * blockDim.x + threadIdx.x;
  if (i >= P_END) return;
  float v;
  if      (i < P_LNW)  { v = ldf(d0b1, i - P_D0B1, f32); }
  else if (i < P_LNB)  { v = ldf(lnw, i - P_LNW, f32); }
  else if (i < P_D0B2) { v = ldf(lnb, i - P_LNB, f32); }
  else if (i < P_D1B1) { v = ldf(d0b2, i - P_D0B2, f32); }
  else if (i < P_D1B2) { v = ldf(d1b1, i - P_D1B1, f32); }
  else if (i < P_BQV)  { v = ldf(d1b2, i - P_D1B2, f32); }
  else if (i < P_BO)   { int k = i - P_BQV; v = ldf(bqkv, (size_t)(k >> 8)*768 + 512 + (k & 255), f32); }
  else if (i < P_NB1)  { v = ldf(bo, i - P_BO, f32); }
  else if (i < P_NB2)  { v = ldf(nb1, i - P_NB1, f32); }
  else if (i < P_GLIN) { v = ldf(nb2, i - P_NB2, f32); }
  else if (i < P_GP3)  { int k = i - P_GLIN;
                         v = sinf(ldf(gp, (size_t)k*6 + 0, f32)) +
                             cosf(ldf(gp, (size_t)k*6 + 1, f32)) +
                             tanhf(ldf(gp, (size_t)k*6 + 2, f32)); }
  else if (i < P_GP4)  { int k = i - P_GP3; v = ldf(gp, (size_t)k*6 + 3, f32); }
  else if (i < P_GP5)  { int k = i - P_GP4; v = ldf(gp, (size_t)k*6 + 4, f32); }
  else                 { int k = i - P_GP5; v = ldf(gp, (size_t)k*6 + 5, f32); }
  wsf[i] = v;
}

// ---------------- fused 8-layer forward, 32 rows/block ----------------
// launch_bounds(256,4): 4 waves/EU -> 4 blocks/CU (LDS 35,328*4 = 141 KB <= 160 KB,
// VGPR must stay <= 128). R3 measured 124 VGPR at (256,2); occupancy was the limiter.
__global__ __launch_bounds__(THREADS, 4)
void vqc_main(const void* __restrict__ x, const bf16* __restrict__ wsb,
              const float* __restrict__ wsf, const int* __restrict__ flag,
              void* __restrict__ out) {
  __shared__ __align__(16) bf16 curT[TM*SC];   // layer input / residual
  __shared__ __align__(16) bf16 buf0[TM*SC];   // scratch: h-chunks / V / new / t1
  __shared__ float red[2*NW*TM];
  __shared__ float rowa[TM], rowb[TM];

  const int tid  = threadIdx.x;
  const int wave = tid >> 6, lane = tid & 63;
  const int quad = lane >> 4, l16 = lane & 15;
  const size_t rowbase = (size_t)blockIdx.x * TM;
  const int f32io = *flag;

  // load x tile
  if (f32io) {
    const float* xf = (const float*)x;
    for (int i = tid; i < TM*Q/4; i += THREADS) {
      int r = i >> 6, c4 = (i & 63) * 4;
      float4 v = *(const float4*)(xf + (rowbase + r)*Q + c4);
      bf16* d = curT + r*SC + c4;
      d[0] = (bf16)v.x; d[1] = (bf16)v.y; d[2] = (bf16)v.z; d[3] = (bf16)v.w;
    }
  } else {
    const bf16* xb = (const bf16*)x;
    for (int i = tid; i < TM*Q/8; i += THREADS) {
      int r = i >> 5, c8 = (i & 31) * 8;
      *(uint4*)(curT + r*SC + c8) = *(const uint4*)(xb + (rowbase + r)*Q + c8);
    }
  }
  __syncthreads();

#pragma unroll 1
  for (int li = 0; li < 8; ++li) {
    const int t = li % 3;
    f32x4 acc2[2][4]; zero_acc<4>(acc2);   // cur_new, cols (nj*4+wave)*16+l16

    if (t == 0) {
      // ---- dense0: h = gelu(LN(cur@w1+b1)) ; cur_new = h@w2+b2 (3 K-chunks) ----
      const int i = li / 3;
      f32x4 acc[2][12]; zero_acc<12>(acc);
      gemm_k256<12>(curT, wsb + W0A_OFF + (size_t)i*768*256, 256, 0, acc, wave, quad, l16);
      const float* b1 = wsf + P_D0B1 + i*768;
#pragma unroll
      for (int nj = 0; nj < 12; ++nj) {
        float bb = b1[(nj*4 + wave)*16 + l16];
#pragma unroll
        for (int mt = 0; mt < 2; ++mt)
#pragma unroll
          for (int reg = 0; reg < 4; ++reg) acc[mt][nj][reg] += bb;
      }
      // LN stats
#pragma unroll
      for (int mt = 0; mt < 2; ++mt) {
#pragma unroll
        for (int reg = 0; reg < 4; ++reg) {
          float sa = 0.f, sb = 0.f;
#pragma unroll
          for (int nj = 0; nj < 12; ++nj) { float v = acc[mt][nj][reg]; sa += v; sb += v*v; }
#pragma unroll
          for (int m = 1; m < 16; m <<= 1) { sa += __shfl_xor(sa, m, 64); sb += __shfl_xor(sb, m, 64); }
          if (l16 == 0) {
            int row = mt*16 + quad*4 + reg;
            red[wave*TM + row] = sa; red[NW*TM + wave*TM + row] = sb;
          }
        }
      }
      __syncthreads();
      if (tid < TM) {
        float sa = 0.f, sb = 0.f;
#pragma unroll
        for (int w = 0; w < NW; ++w) { sa += red[w*TM + tid]; sb += red[NW*TM + w*TM + tid]; }
        float mu  = sa * (1.0f/768.0f);
        float var = sb * (1.0f/768.0f) - mu*mu;
        rowa[tid] = mu; rowb[tid] = rsqrtf(fmaxf(var, 0.f) + 1e-5f);
      }
      __syncthreads();
      const float* lw = wsf + P_LNW + i*768;
      const float* lb = wsf + P_LNB + i*768;
#pragma unroll
      for (int nj = 0; nj < 12; ++nj) {
        int col = (nj*4 + wave)*16 + l16;
        float w_ = lw[col], bb = lb[col];
#pragma unroll
        for (int mt = 0; mt < 2; ++mt)
#pragma unroll
          for (int reg = 0; reg < 4; ++reg) {
            int row = mt*16 + quad*4 + reg;
            acc[mt][nj][reg] = gelu_f((acc[mt][nj][reg] - rowa[row]) * rowb[row] * w_ + bb);
          }
      }
      const bf16* w2 = wsb + W0B_OFF + (size_t)i*256*768;
#pragma unroll 1
      for (int c = 0; c < 3; ++c) {
#pragma unroll
        for (int njl = 0; njl < 4; ++njl) {
          int nj = 4*c + njl;
          int col = (njl*4 + wave)*16 + l16;
#pragma unroll
          for (int mt = 0; mt < 2; ++mt)
#pragma unroll
            for (int reg = 0; reg < 4; ++reg)
              buf0[(mt*16 + quad*4 + reg)*SC + col] = (bf16)acc[mt][nj][reg];
        }
        __syncthreads();
        gemm_k256<4>(buf0, w2, 768, 256*c, acc2, wave, quad, l16);
        __syncthreads();
      }
      addbias4(acc2, wsf + P_D0B2 + i*256, wave, l16);
    } else if (t == 1) {
      // ---- dense1: cur_new = silu(cur@w1+b1) @ w2 + b2 (2 K-chunks) ----
      const int i = (li - 1) / 3;
      f32x4 acc[2][8]; zero_acc<8>(acc);
      gemm_k256<8>(curT, wsb + W1A_OFF + (size_t)i*512*256, 256, 0, acc, wave, quad, l16);
      const float* b1 = wsf + P_D1B1 + i*512;
#pragma unroll
      for (int nj = 0; nj < 8; ++nj) {
        float bb = b1[(nj*4 + wave)*16 + l16];
#pragma unroll
        for (int mt = 0; mt < 2; ++mt)
#pragma unroll
          for (int reg = 0; reg < 4; ++reg) {
            float xv = acc[mt][nj][reg] + bb;
            acc[mt][nj][reg] = xv / (1.0f + __expf(-xv));
          }
      }
      const bf16* w2 = wsb + W1B_OFF + (size_t)i*256*512;
#pragma unroll 1
      for (int c = 0; c < 2; ++c) {
#pragma unroll
        for (int njl = 0; njl < 4; ++njl) {
          int nj = 4*c + njl;
          int col = (njl*4 + wave)*16 + l16;
#pragma unroll
          for (int mt = 0; mt < 2; ++mt)
#pragma unroll
            for (int reg = 0; reg < 4; ++reg)
              buf0[(mt*16 + quad*4 + reg)*SC + col] = (bf16)acc[mt][nj][reg];
        }
        __syncthreads();
        gemm_k256<4>(buf0, w2, 512, 256*c, acc2, wave, quad, l16);
        __syncthreads();
      }
      addbias4(acc2, wsf + P_D1B2 + i*256, wave, l16);
    } else {
      // ---- attention (only V contributes): cur_new = (cur@wv+bqv) @ wo + bo ----
      const int i = (li - 2) / 3;
      f32x4 acc[2][4]; zero_acc<4>(acc);
      gemm_k256<4>(curT, wsb + WV_OFF + (size_t)i*65536, 256, 0, acc, wave, quad, l16);
      addbias4(acc, wsf + P_BQV + i*256, wave, l16);
      store4(buf0, acc, wave, quad, l16);
      __syncthreads();
      gemm_k256<4>(buf0, wsb + WO_OFF + (size_t)i*65536, 256, 0, acc2, wave, quad, l16);
      addbias4(acc2, wsf + P_BO + i*256, wave, l16);
      __syncthreads();
    }

    // ---- entangled ----
    store4(buf0, acc2, wave, quad, l16);
    __syncthreads();
    f32x4 acc3[2][4]; zero_acc<4>(acc3);
    gemm_k256<4>(buf0, wsb + ENT_OFF + (size_t)li*65536, 256, 0, acc3, wave, quad, l16);
    __syncthreads();

    // ---- gate + entangled combine ----
    const float* gl = wsf + P_GLIN + li*256;
    const float* g3 = wsf + P_GP3  + li*256;
    const float* g4 = wsf + P_GP4  + li*256;
    const float* g5 = wsf + P_GP5  + li*256;
#pragma unroll
    for (int nj = 0; nj < 4; ++nj) {
      int col = (nj*4 + wave)*16 + l16;
      float lin = gl[col], p3 = g3[col], p4 = g4[col], p5 = g5[col];
#pragma unroll
      for (int mt = 0; mt < 2; ++mt)
#pragma unroll
        for (int reg = 0; reg < 4; ++reg) {
          float v = acc2[mt][nj][reg];
          float gate = (lin*v + 0.5f*__sinf(p3*v + p4) + 0.5f*__cosf(p5*v)) * 0.25f;
          acc2[mt][nj][reg] = (v + 0.3f*gate + 0.2f*acc3[mt][nj][reg]) * (1.0f/1.5f);
        }
    }

    // ---- nl block on odd layers ----
    if (li & 1) {
      const int j = li >> 1;
      store4(buf0, acc2, wave, quad, l16);
      __syncthreads();
      f32x4 a4[2][4]; zero_acc<4>(a4);
      gemm_k256<4>(buf0, wsb + NL1_OFF + (size_t)j*65536, 256, 0, a4, wave, quad, l16);
      const float* nb1p = wsf + P_NB1 + j*256;
      __syncthreads();
#pragma unroll
      for (int nj = 0; nj < 4; ++nj) {
        int col = (nj*4 + wave)*16 + l16;
        float bb = nb1p[col];
#pragma unroll
        for (int mt = 0; mt < 2; ++mt)
#pragma unroll
          for (int reg = 0; reg < 4; ++reg)
            buf0[(mt*16 + quad*4 + reg)*SC + col] = (bf16)tanh_fast(a4[mt][nj][reg] + bb);
      }
      __syncthreads();
      f32x4 a5[2][4]; zero_acc<4>(a5);
      gemm_k256<4>(buf0, wsb + NL2_OFF + (size_t)j*65536, 256, 0, a5, wave, quad, l16);
      const float* nb2p = wsf + P_NB2 + j*256;
#pragma unroll
      for (int nj = 0; nj < 4; ++nj) {
        float bb = nb2p[(nj*4 + wave)*16 + l16];
#pragma unroll
        for (int mt = 0; mt < 2; ++mt)
#pragma unroll
          for (int reg = 0; reg < 4; ++reg) acc2[mt][nj][reg] += 0.1f*(a5[mt][nj][reg] + bb);
      }
    }

    // ---- residual blend, L2-normalize, tanh, write back ----
    const float alpha = (li < 4) ? 0.8f : 0.6f;
    const float beta  = 1.0f - alpha;
#pragma unroll
    for (int nj = 0; nj < 4; ++nj) {
      int col = (nj*4 + wave)*16 + l16;
#pragma unroll
      for (int mt = 0; mt < 2; ++mt)
#pragma unroll
        for (int reg = 0; reg < 4; ++reg) {
          int row = mt*16 + quad*4 + reg;
          acc2[mt][nj][reg] = alpha*acc2[mt][nj][reg] + beta*(float)curT[row*SC + col];
        }
    }
#pragma unroll
    for (int mt = 0; mt < 2; ++mt) {
#pragma unroll
      for (int reg = 0; reg < 4; ++reg) {
        float s = 0.f;
#pragma unroll
        for (int nj = 0; nj < 4; ++nj) s += acc2[mt][nj][reg]*acc2[mt][nj][reg];
#pragma unroll
        for (int m = 1; m < 16; m <<= 1) s += __shfl_xor(s, m, 64);
        if (l16 == 0) red[wave*TM + mt*16 + quad*4 + reg] = s;
      }
    }
    __syncthreads();
    if (tid < TM) {
      float s = 0.f;
#pragma unroll
      for (int w = 0; w < NW; ++w) s += red[w*TM + tid];
      rowa[tid] = 1.0f / (sqrtf(fmaxf(s, 0.f)) + 1e-8f);
    }
    __syncthreads();
#pragma unroll
    for (int nj = 0; nj < 4; ++nj) {
      int col = (nj*4 + wave)*16 + l16;
#pragma unroll
      for (int mt = 0; mt < 2; ++mt)
#pragma unroll
        for (int reg = 0; reg < 4; ++reg) {
          int row = mt*16 + quad*4 + reg;
          curT[row*SC + col] = (bf16)tanh_fast(acc2[mt][nj][reg] * rowa[row]);
        }
    }
    __syncthreads();
  }

  // write result tile (dtype matches input dtype)
  if (f32io) {
    float* of = (float*)out;
    for (int i = tid; i < TM*Q/4; i += THREADS) {
      int r = i >> 6, c4 = (i & 63) * 4;
      const bf16* s = curT + r*SC + c4;
      float4 v = make_float4((float)s[0], (float)s[1], (float)s[2], (float)s[3]);
      *(float4*)(of + (rowbase + r)*Q + c4) = v;
    }
  } else {
    bf16* ob = (bf16*)out;
    for (int i = tid; i < TM*Q/8; i += THREADS) {
      int r = i >> 5, c8 = (i & 31) * 8;
      *(uint4*)(ob + (rowbase + r)*Q + c8) = *(const uint4*)(curT + r*SC + c8);
    }
  }
}

// ---------------- host entry ----------------
extern "C" void kernel_launch(void* const* d_in, const int* in_sizes, int n_in,
                              void* d_out, int out_size, void* d_ws, size_t ws_size,
                              hipStream_t stream) {
  const void* x    = d_in[0];
  const void* d0w1 = d_in[1];
  const void* d0b1 = d_in[2];
  const void* lnw  = d_in[3];
  const void* lnb  = d_in[4];
  const void* d0w2 = d_in[5];
  const void* d0b2 = d_in[6];
  const void* d1w1 = d_in[7];
  const void* d1b1 = d_in[8];
  const void* d1w2 = d_in[9];
  const void* d1b2 = d_in[10];
  const void* wqkv = d_in[11];
  const void* bqkv = d_in[12];
  const void* wo   = d_in[13];
  const void* bo   = d_in[14];
  const void* gp   = d_in[15];
  const void* ent  = d_in[16];
  const void* nl1  = d_in[17];
  const void* nb1  = d_in[18];
  const void* nl2  = d_in[19];
  const void* nb2  = d_in[20];

  bf16*  wsb  = (bf16*)d_ws;
  float* wsf  = (float*)((char*)d_ws + F32_BYTE_OFF);
  int*   flag = (int*)((char*)d_ws + FLAG_OFF);

  detect_dtype<<<dim3(1), dim3(256), 0, stream>>>((const uint16_t*)x, flag);
  pack_weights<<<dim3(48, 32), dim3(256), 0, stream>>>(
      d0w1, d0w2, d1w1, d1w2, wqkv, wo, ent, nl1, nl2, wsb, flag);
  pack_params<<<dim3((P_END + 255)/256), dim3(256), 0, stream>>>(
      d0b1, lnw, lnb, d0b2, d1b1, d1b2, bqkv, bo, gp, nb1, nb2, wsf, flag);
  vqc_main<<<dim3(NBLK), dim3(THREADS), 0, stream>>>(x, wsb, wsf, flag, d_out);
}

// Round 6
// 1685.280 us; speedup vs baseline: 1.6095x; 1.6095x over previous
//
#include <hip/hip_runtime.h>
#include <stdint.h>

#define DI __device__ __forceinline__

typedef __bf16 bf16;
typedef __bf16 bf16x8 __attribute__((ext_vector_type(8)));
typedef float  f32x4  __attribute__((ext_vector_type(4)));

// ---------------- problem constants ----------------
constexpr int Q = 256;
constexpr int BATCH = 65536;
constexpr int TM = 64;              // rows per block
constexpr int THREADS = 512;        // 8 waves (R6: spreads acc across waves, no reg-packing)
constexpr int NW = 8;
constexpr int NBLK = BATCH / TM;    // 1024
constexpr int SC = Q + 8;           // LDS row stride

// ---------------- workspace layout (packed bf16 weights, Wt[N][K] row-major) ----------------
constexpr int W0A_OFF = 0;                         // 3 x (768x256)
constexpr int W0B_OFF = W0A_OFF + 3*768*256;       // 3 x (256x768)
constexpr int W1A_OFF = W0B_OFF + 3*256*768;       // 3 x (512x256)
constexpr int W1B_OFF = W1A_OFF + 3*512*256;       // 3 x (256x512)
constexpr int WV_OFF  = W1B_OFF + 3*256*512;       // 2 x (256x256)  wqkv V-slice
constexpr int WO_OFF  = WV_OFF  + 2*256*256;       // 2 x (256x256)
constexpr int ENT_OFF = WO_OFF  + 2*256*256;       // 8 x (256x256)  tanh pre-applied
constexpr int NL1_OFF = ENT_OFF + 8*256*256;       // 4 x (256x256)
constexpr int NL2_OFF = NL1_OFF + 4*256*256;       // 4 x (256x256)
constexpr int WEND    = NL2_OFF + 4*256*256;
constexpr size_t F32_BYTE_OFF = (((size_t)WEND*2) + 255) & ~(size_t)255;

// f32 param region (element offsets)
constexpr int P_D0B1 = 0;                  // 3*768
constexpr int P_LNW  = P_D0B1 + 3*768;
constexpr int P_LNB  = P_LNW  + 3*768;
constexpr int P_D0B2 = P_LNB  + 3*768;     // 3*256
constexpr int P_D1B1 = P_D0B2 + 3*256;     // 3*512
constexpr int P_D1B2 = P_D1B1 + 3*512;     // 3*256
constexpr int P_BQV  = P_D1B2 + 3*256;     // 2*256
constexpr int P_BO   = P_BQV  + 2*256;     // 2*256
constexpr int P_NB1  = P_BO   + 2*256;     // 4*256
constexpr int P_NB2  = P_NB1  + 4*256;     // 4*256
constexpr int P_GLIN = P_NB2  + 4*256;     // 8*256
constexpr int P_GP3  = P_GLIN + 8*256;
constexpr int P_GP4  = P_GP3  + 8*256;
constexpr int P_GP5  = P_GP4  + 8*256;
constexpr int P_END  = P_GP5  + 8*256;     // 21,248 floats
constexpr size_t FLAG_OFF = F32_BYTE_OFF + (size_t)P_END*4;   // one int

// ---------------- dual-dtype load helper ----------------
DI float ldf(const void* p, size_t idx, int f32) {
  return f32 ? ((const float*)p)[idx] : (float)((const bf16*)p)[idx];
}

// ---------------- device math helpers ----------------
DI float tanh_fast(float x) {
  float ax = fabsf(x);
  float e  = __expf(-2.0f * ax);
  float r  = (1.0f - e) / (1.0f + e);
  return copysignf(r, x);
}

DI float gelu_f(float x) {   // exact-gelu via A&S 7.1.26 erf
  float ax = fabsf(x) * 0.70710678118654752f;
  float t  = 1.0f / (1.0f + 0.3275911f * ax);
  float y  = t*(0.254829592f + t*(-0.284496736f + t*(1.421413741f +
             t*(-1.453152027f + t*1.061405429f))));
  float er = copysignf(1.0f - y * __expf(-ax*ax), x);
  return 0.5f * x * (1.0f + er);
}

DI f32x4 mfma_bf16(uint4 a, uint4 b, f32x4 c) {
  return __builtin_amdgcn_mfma_f32_16x16x32_bf16(
      __builtin_bit_cast(bf16x8, a), __builtin_bit_cast(bf16x8, b), c, 0, 0, 0);
}

template<int NJ>
DI void zero_acc(f32x4 (&a)[4][NJ]) {
#pragma unroll
  for (int i = 0; i < 4; ++i)
#pragma unroll
    for (int j = 0; j < NJ; ++j) a[i][j] = f32x4{0.f, 0.f, 0.f, 0.f};
}

// D(64 x 16*NW*NJ) += A(64x256 LDS, stride SC) * B-chunk from packed Bt[N][kdb],
// k in [koff, koff+256). n-tile index = nj*NW + wave.
template<int NJ>
DI void gemm_k256(const bf16* A, const bf16* __restrict__ Bt, int kdb, int koff,
                  f32x4 (&acc)[4][NJ], int wave, int quad, int l16) {
  const bf16* ar[4];
#pragma unroll
  for (int mt = 0; mt < 4; ++mt) ar[mt] = A + (mt*16 + l16)*SC + quad*8;
  const bf16* br[NJ];
#pragma unroll
  for (int nj = 0; nj < NJ; ++nj)
    br[nj] = Bt + (size_t)((nj*NW + wave)*16 + l16)*kdb + koff + quad*8;
#pragma unroll
  for (int ks = 0; ks < 8; ++ks) {
    uint4 av[4];
#pragma unroll
    for (int mt = 0; mt < 4; ++mt) av[mt] = *(const uint4*)(ar[mt] + ks*32);
#pragma unroll
    for (int nj = 0; nj < NJ; ++nj) {
      uint4 bv = *(const uint4*)(br[nj] + ks*32);
#pragma unroll
      for (int mt = 0; mt < 4; ++mt) acc[mt][nj] = mfma_bf16(av[mt], bv, acc[mt][nj]);
    }
  }
}

template<int NJ>
DI void addbias(f32x4 (&a)[4][NJ], const float* __restrict__ b, int wave, int l16) {
#pragma unroll
  for (int nj = 0; nj < NJ; ++nj) {
    float bb = b[(nj*NW + wave)*16 + l16];
#pragma unroll
    for (int mt = 0; mt < 4; ++mt)
#pragma unroll
      for (int reg = 0; reg < 4; ++reg) a[mt][nj][reg] += bb;
  }
}

template<int NJ>
DI void store_t(bf16* dst, const f32x4 (&a)[4][NJ], int wave, int quad, int l16) {
#pragma unroll
  for (int nj = 0; nj < NJ; ++nj) {
    int col = (nj*NW + wave)*16 + l16;
#pragma unroll
    for (int mt = 0; mt < 4; ++mt)
#pragma unroll
      for (int reg = 0; reg < 4; ++reg)
        dst[(mt*16 + quad*4 + reg)*SC + col] = (bf16)a[mt][nj][reg];
  }
}

// ---------------- dtype detector ----------------
__global__ void detect_dtype(const uint16_t* __restrict__ xr, int* __restrict__ flag) {
  __shared__ int s_max;
  if (threadIdx.x == 0) s_max = 0;
  __syncthreads();
  int e = 0;
  for (int i = threadIdx.x; i < 4096; i += 256) {
    int ex = (xr[2*i] >> 7) & 0xFF;
    e = e > ex ? e : ex;
  }
  atomicMax(&s_max, e);
  __syncthreads();
  if (threadIdx.x == 0) *flag = (s_max >= 140) ? 1 : 0;
}

// ---------------- weight repack: W(KxN) -> Wt(NxK) bf16, optional tanh ----------------
__global__ void pack_weights(const void* __restrict__ d0w1, const void* __restrict__ d0w2,
                             const void* __restrict__ d1w1, const void* __restrict__ d1w2,
                             const void* __restrict__ wqkv, const void* __restrict__ wo,
                             const void* __restrict__ ent,  const void* __restrict__ nl1,
                             const void* __restrict__ nl2,  bf16* __restrict__ wsb,
                             const int* __restrict__ flag) {
  const int f32 = *flag;
  int job = blockIdx.y;
  const void* src; int mi, K, N, srcN, col0 = 0, dtanh = 0; long dst;
  if      (job < 3)  { src=d0w1; mi=job;    K=256; N=768; srcN=768; dst=W0A_OFF + (long)mi*768*256; }
  else if (job < 6)  { src=d0w2; mi=job-3;  K=768; N=256; srcN=256; dst=W0B_OFF + (long)mi*256*768; }
  else if (job < 9)  { src=d1w1; mi=job-6;  K=256; N=512; srcN=512; dst=W1A_OFF + (long)mi*512*256; }
  else if (job < 12) { src=d1w2; mi=job-9;  K=512; N=256; srcN=256; dst=W1B_OFF + (long)mi*256*512; }
  else if (job < 14) { src=wqkv; mi=job-12; K=256; N=256; srcN=768; col0=512; dst=WV_OFF + (long)mi*65536; }
  else if (job < 16) { src=wo;   mi=job-14; K=256; N=256; srcN=256; dst=WO_OFF + (long)mi*65536; }
  else if (job < 24) { src=ent;  mi=job-16; K=256; N=256; srcN=256; dst=ENT_OFF + (long)mi*65536; dtanh=1; }
  else if (job < 28) { src=nl1;  mi=job-24; K=256; N=256; srcN=256; dst=NL1_OFF + (long)mi*65536; }
  else               { src=nl2;  mi=job-28; K=256; N=256; srcN=256; dst=NL2_OFF + (long)mi*65536; }
  const size_t base = (size_t)mi * K * srcN;

  int tk = K/64, tn = N/64;
  int tile = blockIdx.x;
  if (tile >= tk*tn) return;
  int ik = tile % tk, in_ = tile / tk;

  __shared__ float t[64][65];
  int tid = threadIdx.x;
  for (int e = tid; e < 4096; e += 256) {
    int r = e >> 6, c = e & 63;
    t[r][c] = ldf(src, base + (size_t)(ik*64 + r)*srcN + col0 + in_*64 + c, f32);
  }
  __syncthreads();
  for (int e = tid; e < 4096; e += 256) {
    int nr = e >> 6, kc = e & 63;
    float v = t[kc][nr];
    if (dtanh) v = tanhf(v);
    wsb[dst + (size_t)(in_*64 + nr)*K + ik*64 + kc] = (bf16)v;
  }
}

// ---------------- param repack ----------------
__global__ void pack_params(const void* __restrict__ d0b1, const void* __restrict__ lnw,
                            const void* __restrict__ lnb,  const void* __restrict__ d0b2,
                            const void* __restrict__ d1b1, const void* __restrict__ d1b2,
                            const void* __restrict__ bqkv, const void* __restrict__ bo,
                            const void* __restrict__ gp,   const void* __restrict__ nb1,
                            const void* __restrict__ nb2,  float* __restrict__ wsf,
                            const int* __restrict__ flag) {
  const int f32 = *flag;
  int i = blockIdx.x * blockDim.x + threadIdx.x;
  if (i >= P_END) return;
  float v;
  if      (i < P_LNW)  { v = ldf(d0b1, i - P_D0B1, f32); }
  else if (i < P_LNB)  { v = ldf(lnw, i - P_LNW, f32); }
  else if (i < P_D0B2) { v = ldf(lnb, i - P_LNB, f32); }
  else if (i < P_D1B1) { v = ldf(d0b2, i - P_D0B2, f32); }
  else if (i < P_D1B2) { v = ldf(d1b1, i - P_D1B1, f32); }
  else if (i < P_BQV)  { v = ldf(d1b2, i - P_D1B2, f32); }
  else if (i < P_BO)   { int k = i - P_BQV; v = ldf(bqkv, (size_t)(k >> 8)*768 + 512 + (k & 255), f32); }
  else if (i < P_NB1)  { v = ldf(bo, i - P_BO, f32); }
  else if (i < P_NB2)  { v = ldf(nb1, i - P_NB1, f32); }
  else if (i < P_GLIN) { v = ldf(nb2, i - P_NB2, f32); }
  else if (i < P_GP3)  { int k = i - P_GLIN;
                         v = sinf(ldf(gp, (size_t)k*6 + 0, f32)) +
                             cosf(ldf(gp, (size_t)k*6 + 1, f32)) +
                             tanhf(ldf(gp, (size_t)k*6 + 2, f32)); }
  else if (i < P_GP4)  { int k = i - P_GP3; v = ldf(gp, (size_t)k*6 + 3, f32); }
  else if (i < P_GP5)  { int k = i - P_GP4; v = ldf(gp, (size_t)k*6 + 4, f32); }
  else                 { int k = i - P_GP5; v = ldf(gp, (size_t)k*6 + 5, f32); }
  wsf[i] = v;
}

// ---------------- fused 8-layer forward, 64 rows/block, 8 waves ----------------
// (512,2): cap 256 VGPR. 8 waves spread the dense0 accumulator to acc[4][6] (96 regs)
// so h stays in plain f32 registers across the chunk loop (R3-proven structure, no
// bf16 register packing, no dynamic-indexed mega-arrays).
__global__ __launch_bounds__(THREADS, 2)
void vqc_main(const void* __restrict__ x, const bf16* __restrict__ wsb,
              const float* __restrict__ wsf, const int* __restrict__ flag,
              void* __restrict__ out) {
  __shared__ __align__(16) bf16 curT[TM*SC];   // layer input / residual (64x264)
  __shared__ __align__(16) bf16 buf0[TM*SC];   // scratch: h-chunks / V / new / t1
  __shared__ float red[2*NW*TM];               // 1024 floats
  __shared__ float rowa[TM], rowb[TM];

  const int tid  = threadIdx.x;
  const int wave = tid >> 6, lane = tid & 63;
  const int quad = lane >> 4, l16 = lane & 15;
  const size_t rowbase = (size_t)blockIdx.x * TM;
  const int f32io = *flag;

  // load x tile
  if (f32io) {
    const float* xf = (const float*)x;
    for (int i = tid; i < TM*Q/4; i += THREADS) {
      int r = i >> 6, c4 = (i & 63) * 4;
      float4 v = *(const float4*)(xf + (rowbase + r)*Q + c4);
      bf16* d = curT + r*SC + c4;
      d[0] = (bf16)v.x; d[1] = (bf16)v.y; d[2] = (bf16)v.z; d[3] = (bf16)v.w;
    }
  } else {
    const bf16* xb = (const bf16*)x;
    for (int i = tid; i < TM*Q/8; i += THREADS) {
      int r = i >> 5, c8 = (i & 31) * 8;
      *(uint4*)(curT + r*SC + c8) = *(const uint4*)(xb + (rowbase + r)*Q + c8);
    }
  }
  __syncthreads();

#pragma unroll 1
  for (int li = 0; li < 8; ++li) {
    const int t = li % 3;
    f32x4 acc2[4][2]; zero_acc<2>(acc2);   // cur_new, cols (nj*8+wave)*16+l16

    if (t == 0) {
      // ---- dense0: h = gelu(LN(cur@w1+b1)) ; cur_new = h@w2+b2 (3 K-chunks) ----
      const int i = li / 3;
      f32x4 acc[4][6]; zero_acc<6>(acc);
      gemm_k256<6>(curT, wsb + W0A_OFF + (size_t)i*768*256, 256, 0, acc, wave, quad, l16);
      const float* b1 = wsf + P_D0B1 + i*768;
#pragma unroll
      for (int nj = 0; nj < 6; ++nj) {
        float bb = b1[(nj*NW + wave)*16 + l16];
#pragma unroll
        for (int mt = 0; mt < 4; ++mt)
#pragma unroll
          for (int reg = 0; reg < 4; ++reg) acc[mt][nj][reg] += bb;
      }
      // LN stats (each wave: 6 nj x 16 l16-cols = 96 cols; cross-wave via red)
#pragma unroll
      for (int mt = 0; mt < 4; ++mt) {
#pragma unroll
        for (int reg = 0; reg < 4; ++reg) {
          float sa = 0.f, sb = 0.f;
#pragma unroll
          for (int nj = 0; nj < 6; ++nj) { float v = acc[mt][nj][reg]; sa += v; sb += v*v; }
#pragma unroll
          for (int m = 1; m < 16; m <<= 1) { sa += __shfl_xor(sa, m, 64); sb += __shfl_xor(sb, m, 64); }
          if (l16 == 0) {
            int row = mt*16 + quad*4 + reg;
            red[wave*TM + row] = sa; red[NW*TM + wave*TM + row] = sb;
          }
        }
      }
      __syncthreads();
      if (tid < TM) {
        float sa = 0.f, sb = 0.f;
#pragma unroll
        for (int w = 0; w < NW; ++w) { sa += red[w*TM + tid]; sb += red[NW*TM + w*TM + tid]; }
        float mu  = sa * (1.0f/768.0f);
        float var = sb * (1.0f/768.0f) - mu*mu;
        rowa[tid] = mu; rowb[tid] = rsqrtf(fmaxf(var, 0.f) + 1e-5f);
      }
      __syncthreads();
      const float* lw = wsf + P_LNW + i*768;
      const float* lb = wsf + P_LNB + i*768;
#pragma unroll
      for (int nj = 0; nj < 6; ++nj) {
        int col = (nj*NW + wave)*16 + l16;
        float w_ = lw[col], bb = lb[col];
#pragma unroll
        for (int mt = 0; mt < 4; ++mt)
#pragma unroll
          for (int reg = 0; reg < 4; ++reg) {
            int row = mt*16 + quad*4 + reg;
            acc[mt][nj][reg] = gelu_f((acc[mt][nj][reg] - rowa[row]) * rowb[row] * w_ + bb);
          }
      }
      const bf16* w2 = wsb + W0B_OFF + (size_t)i*256*768;
#pragma unroll 1
      for (int c = 0; c < 3; ++c) {      // K-chunked h @ w2; chunk c = h-cols [256c,256c+256)
#pragma unroll
        for (int njl = 0; njl < 2; ++njl) {
          int nj = 2*c + njl;
          int col = (njl*NW + wave)*16 + l16;
#pragma unroll
          for (int mt = 0; mt < 4; ++mt)
#pragma unroll
            for (int reg = 0; reg < 4; ++reg)
              buf0[(mt*16 + quad*4 + reg)*SC + col] = (bf16)acc[mt][nj][reg];
        }
        __syncthreads();
        gemm_k256<2>(buf0, w2, 768, 256*c, acc2, wave, quad, l16);
        __syncthreads();
      }
      addbias<2>(acc2, wsf + P_D0B2 + i*256, wave, l16);
    } else if (t == 1) {
      // ---- dense1: cur_new = silu(cur@w1+b1) @ w2 + b2 (2 K-chunks) ----
      const int i = (li - 1) / 3;
      f32x4 acc[4][4]; zero_acc<4>(acc);
      gemm_k256<4>(curT, wsb + W1A_OFF + (size_t)i*512*256, 256, 0, acc, wave, quad, l16);
      const float* b1 = wsf + P_D1B1 + i*512;
#pragma unroll
      for (int nj = 0; nj < 4; ++nj) {
        float bb = b1[(nj*NW + wave)*16 + l16];
#pragma unroll
        for (int mt = 0; mt < 4; ++mt)
#pragma unroll
          for (int reg = 0; reg < 4; ++reg) {
            float xv = acc[mt][nj][reg] + bb;
            acc[mt][nj][reg] = xv / (1.0f + __expf(-xv));
          }
      }
      const bf16* w2 = wsb + W1B_OFF + (size_t)i*256*512;
#pragma unroll 1
      for (int c = 0; c < 2; ++c) {
#pragma unroll
        for (int njl = 0; njl < 2; ++njl) {
          int nj = 2*c + njl;
          int col = (njl*NW + wave)*16 + l16;
#pragma unroll
          for (int mt = 0; mt < 4; ++mt)
#pragma unroll
            for (int reg = 0; reg < 4; ++reg)
              buf0[(mt*16 + quad*4 + reg)*SC + col] = (bf16)acc[mt][nj][reg];
        }
        __syncthreads();
        gemm_k256<2>(buf0, w2, 512, 256*c, acc2, wave, quad, l16);
        __syncthreads();
      }
      addbias<2>(acc2, wsf + P_D1B2 + i*256, wave, l16);
    } else {
      // ---- attention (only V contributes): cur_new = (cur@wv+bqv) @ wo + bo ----
      const int i = (li - 2) / 3;
      f32x4 acc[4][2]; zero_acc<2>(acc);
      gemm_k256<2>(curT, wsb + WV_OFF + (size_t)i*65536, 256, 0, acc, wave, quad, l16);
      addbias<2>(acc, wsf + P_BQV + i*256, wave, l16);
      store_t<2>(buf0, acc, wave, quad, l16);
      __syncthreads();
      gemm_k256<2>(buf0, wsb + WO_OFF + (size_t)i*65536, 256, 0, acc2, wave, quad, l16);
      addbias<2>(acc2, wsf + P_BO + i*256, wave, l16);
      __syncthreads();
    }

    // ---- entangled ----
    store_t<2>(buf0, acc2, wave, quad, l16);
    __syncthreads();
    f32x4 acc3[4][2]; zero_acc<2>(acc3);
    gemm_k256<2>(buf0, wsb + ENT_OFF + (size_t)li*65536, 256, 0, acc3, wave, quad, l16);
    __syncthreads();

    // ---- gate + entangled combine ----
    const float* gl = wsf + P_GLIN + li*256;
    const float* g3 = wsf + P_GP3  + li*256;
    const float* g4 = wsf + P_GP4  + li*256;
    const float* g5 = wsf + P_GP5  + li*256;
#pragma unroll
    for (int nj = 0; nj < 2; ++nj) {
      int col = (nj*NW + wave)*16 + l16;
      float lin = gl[col], p3 = g3[col], p4 = g4[col], p5 = g5[col];
#pragma unroll
      for (int mt = 0; mt < 4; ++mt)
#pragma unroll
        for (int reg = 0; reg < 4; ++reg) {
          float v = acc2[mt][nj][reg];
          float gate = (lin*v + 0.5f*__sinf(p3*v + p4) + 0.5f*__cosf(p5*v)) * 0.25f;
          acc2[mt][nj][reg] = (v + 0.3f*gate + 0.2f*acc3[mt][nj][reg]) * (1.0f/1.5f);
        }
    }

    // ---- nl block on odd layers ----
    if (li & 1) {
      const int j = li >> 1;
      store_t<2>(buf0, acc2, wave, quad, l16);
      __syncthreads();
      f32x4 a4[4][2]; zero_acc<2>(a4);
      gemm_k256<2>(buf0, wsb + NL1_OFF + (size_t)j*65536, 256, 0, a4, wave, quad, l16);
      const float* nb1p = wsf + P_NB1 + j*256;
      __syncthreads();                    // nl1 reads done -> buf0 reusable
#pragma unroll
      for (int nj = 0; nj < 2; ++nj) {
        int col = (nj*NW + wave)*16 + l16;
        float bb = nb1p[col];
#pragma unroll
        for (int mt = 0; mt < 4; ++mt)
#pragma unroll
          for (int reg = 0; reg < 4; ++reg)
            buf0[(mt*16 + quad*4 + reg)*SC + col] = (bf16)tanh_fast(a4[mt][nj][reg] + bb);
      }
      __syncthreads();
      f32x4 a5[4][2]; zero_acc<2>(a5);
      gemm_k256<2>(buf0, wsb + NL2_OFF + (size_t)j*65536, 256, 0, a5, wave, quad, l16);
      const float* nb2p = wsf + P_NB2 + j*256;
#pragma unroll
      for (int nj = 0; nj < 2; ++nj) {
        float bb = nb2p[(nj*NW + wave)*16 + l16];
#pragma unroll
        for (int mt = 0; mt < 4; ++mt)
#pragma unroll
          for (int reg = 0; reg < 4; ++reg) acc2[mt][nj][reg] += 0.1f*(a5[mt][nj][reg] + bb);
      }
    }

    // ---- residual blend, L2-normalize, tanh, write back ----
    const float alpha = (li < 4) ? 0.8f : 0.6f;
    const float beta  = 1.0f - alpha;
#pragma unroll
    for (int nj = 0; nj < 2; ++nj) {
      int col = (nj*NW + wave)*16 + l16;
#pragma unroll
      for (int mt = 0; mt < 4; ++mt)
#pragma unroll
        for (int reg = 0; reg < 4; ++reg) {
          int row = mt*16 + quad*4 + reg;
          acc2[mt][nj][reg] = alpha*acc2[mt][nj][reg] + beta*(float)curT[row*SC + col];
        }
    }
#pragma unroll
    for (int mt = 0; mt < 4; ++mt) {
#pragma unroll
      for (int reg = 0; reg < 4; ++reg) {
        float s = 0.f;
#pragma unroll
        for (int nj = 0; nj < 2; ++nj) s += acc2[mt][nj][reg]*acc2[mt][nj][reg];
#pragma unroll
        for (int m = 1; m < 16; m <<= 1) s += __shfl_xor(s, m, 64);
        if (l16 == 0) red[wave*TM + mt*16 + quad*4 + reg] = s;
      }
    }
    __syncthreads();
    if (tid < TM) {
      float s = 0.f;
#pragma unroll
      for (int w = 0; w < NW; ++w) s += red[w*TM + tid];
      rowa[tid] = 1.0f / (sqrtf(fmaxf(s, 0.f)) + 1e-8f);
    }
    __syncthreads();
#pragma unroll
    for (int nj = 0; nj < 2; ++nj) {
      int col = (nj*NW + wave)*16 + l16;
#pragma unroll
      for (int mt = 0; mt < 4; ++mt)
#pragma unroll
        for (int reg = 0; reg < 4; ++reg) {
          int row = mt*16 + quad*4 + reg;
          curT[row*SC + col] = (bf16)tanh_fast(acc2[mt][nj][reg] * rowa[row]);
        }
    }
    __syncthreads();
  }

  // write result tile (dtype matches input dtype)
  if (f32io) {
    float* of = (float*)out;
    for (int i = tid; i < TM*Q/4; i += THREADS) {
      int r = i >> 6, c4 = (i & 63) * 4;
      const bf16* s = curT + r*SC + c4;
      float4 v = make_float4((float)s[0], (float)s[1], (float)s[2], (float)s[3]);
      *(float4*)(of + (rowbase + r)*Q + c4) = v;
    }
  } else {
    bf16* ob = (bf16*)out;
    for (int i = tid; i < TM*Q/8; i += THREADS) {
      int r = i >> 5, c8 = (i & 31) * 8;
      *(uint4*)(ob + (rowbase + r)*Q + c8) = *(const uint4*)(curT + r*SC + c8);
    }
  }
}

// ---------------- host entry ----------------
extern "C" void kernel_launch(void* const* d_in, const int* in_sizes, int n_in,
                              void* d_out, int out_size, void* d_ws, size_t ws_size,
                              hipStream_t stream) {
  const void* x    = d_in[0];
  const void* d0w1 = d_in[1];
  const void* d0b1 = d_in[2];
  const void* lnw  = d_in[3];
  const void* lnb  = d_in[4];
  const void* d0w2 = d_in[5];
  const void* d0b2 = d_in[6];
  const void* d1w1 = d_in[7];
  const void* d1b1 = d_in[8];
  const void* d1w2 = d_in[9];
  const void* d1b2 = d_in[10];
  const void* wqkv = d_in[11];
  const void* bqkv = d_in[12];
  const void* wo   = d_in[13];
  const void* bo   = d_in[14];
  const void* gp   = d_in[15];
  const void* ent  = d_in[16];
  const void* nl1  = d_in[17];
  const void* nb1  = d_in[18];
  const void* nl2  = d_in[19];
  const void* nb2  = d_in[20];

  bf16*  wsb  = (bf16*)d_ws;
  float* wsf  = (float*)((char*)d_ws + F32_BYTE_OFF);
  int*   flag = (int*)((char*)d_ws + FLAG_OFF);

  detect_dtype<<<dim3(1), dim3(256), 0, stream>>>((const uint16_t*)x, flag);
  pack_weights<<<dim3(48, 32), dim3(256), 0, stream>>>(
      d0w1, d0w2, d1w1, d1w2, wqkv, wo, ent, nl1, nl2, wsb, flag);
  pack_params<<<dim3((P_END + 255)/256), dim3(256), 0, stream>>>(
      d0b1, lnw, lnb, d0b2, d1b1, d1b2, bqkv, bo, gp, nb1, nb2, wsf, flag);
  vqc_main<<<dim3(NBLK), dim3(THREADS), 0, stream>>>(x, wsb, wsf, flag, d_out);
}